// Round 12
// baseline (246.055 us; speedup 1.0000x reference)
//
#include <hip/hip_runtime.h>
#include <hip/hip_bf16.h>
#include <stdint.h>

// Problem constants (fixed by the reference)
#define NS   8192
#define XD   512
#define HD   2048
#define YD   512

typedef unsigned short u16;
using bf16x8 = __attribute__((ext_vector_type(8))) short;
using f32x4  = __attribute__((ext_vector_type(4))) float;

__device__ __forceinline__ float bf2f(u16 u) {
  union { uint32_t i; float f; } v; v.i = ((uint32_t)u) << 16; return v.f;
}
__device__ __forceinline__ u16 f2b(float f) {
  __hip_bfloat16 hb = __float2bfloat16(f);
  return *(const u16*)&hb;
}
// dtype-adaptive element load: f32 flag ? read float : read bf16
__device__ __forceinline__ float ld_in(const void* p, int f32, size_t i) {
  return f32 ? ((const float*)p)[i] : bf2f(((const u16*)p)[i]);
}
#define GLDS(gp, lp) __builtin_amdgcn_global_load_lds( \
    (__attribute__((address_space(1))) void*)(gp),     \
    (__attribute__((address_space(3))) void*)(lp), 16, 0, 0)

// ---------------- per-block dtype self-detection ----------------------------
// (round-2/3 lesson: inputs are MIXED dtype; accounting says x,y = fp32,
// weights/biases = bf16 — but stay adaptive). fp32 bits read as bf16 are
// wild/NaN with p~0.46 per low-u16 -> 256+ sample probe is conclusive.
__device__ __forceinline__ int probe_f32(const void* p, int n_u16, int* sflag) {
  if (threadIdx.x == 0) *sflag = 0;
  __syncthreads();
  const u16* q = (const u16*)p;
  int wild = 0;
  for (int i = threadIdx.x; i < n_u16; i += blockDim.x) {
    float v = bf2f(q[i]);
    if (!(fabsf(v) <= 1000.0f)) wild = 1;   // catches huge AND NaN
  }
  if (wild) *sflag = 1;
  __syncthreads();
  int r = *sflag;
  __syncthreads();                          // safe for back-to-back reuse
  return r;
}

// ---------------- shared 64x64 transpose tile (bf16/f32 in -> bf16^T out) ---
__device__ __forceinline__ void transpose64(const void* in, u16* out,
                                            int R, int C, int f, int t,
                                            u16* tile /* >= 64*72 u16 */) {
  const int tid = threadIdx.x;
  const int nbx = C >> 6;
  const int c0 = (t % nbx) * 64, r0 = (t / nbx) * 64;
  const int r = tid >> 2, cc = (tid & 3) * 16;
  if (f) {
    const float4* s = (const float4*)((const float*)in + (size_t)(r0 + r) * C + c0 + cc);
#pragma unroll
    for (int k = 0; k < 4; ++k) {
      float4 v = s[k];
      tile[r * 72 + cc + k * 4 + 0] = f2b(v.x);
      tile[r * 72 + cc + k * 4 + 1] = f2b(v.y);
      tile[r * 72 + cc + k * 4 + 2] = f2b(v.z);
      tile[r * 72 + cc + k * 4 + 3] = f2b(v.w);
    }
  } else {
    const uint4* s = (const uint4*)((const u16*)in + (size_t)(r0 + r) * C + c0 + cc);
    *(uint4*)&tile[r * 72 + cc]     = s[0];
    *(uint4*)&tile[r * 72 + cc + 8] = s[1];
  }
  __syncthreads();
  const int i = tid >> 2, jc = (tid & 3) * 16;
  alignas(16) u16 o[16];
#pragma unroll
  for (int j = 0; j < 16; ++j) o[j] = tile[(jc + j) * 72 + i];
  uint4* dq = (uint4*)&out[(size_t)(c0 + i) * R + r0 + jc];
  dq[0] = ((const uint4*)o)[0];
  dq[1] = ((const uint4*)o)[1];
}

// ---------------- fused prep: x->bf16, biases, all 4 transposes -------------
// (R12: exactly R10's content — the config where prep never hit the top-5.
//  ystats moved to gemm2's head: R9-R11 priced every other placement at
//  +8..+15 us to its host; gemm2 has the smallest skew denominator.)
// grid: [0,2048) x-convert | 2048 biases | [2049,3073) transposes
// biasv layout: [b1m(2048) | b1l(2048) | b2m(512) | b2l(512)]
// W1t combined: [4096, 512] = W1m^T rows 0..2047, W1l^T rows 2048..4095.
__global__ __launch_bounds__(256) void prep_all(
    const void* __restrict__ x,
    const void* w1m, const void* b1m, const void* w2m, const void* b2m,
    const void* w1l, const void* b1l, const void* w2l, const void* b2l,
    u16* __restrict__ xb, float* __restrict__ biasv,
    u16* __restrict__ W1t, u16* __restrict__ W2tm, u16* __restrict__ W2tl) {
  __shared__ u16 tile[64 * 72];              // transpose staging (9216 B)
  __shared__ int sflag;
  const int b = blockIdx.x;
  const int tid = threadIdx.x;

  if (b < 2048) {                            // ---- x conversion (f32 only)
    if (!probe_f32(x, 1024, &sflag)) return; // bf16 -> gemm1 reads x directly
    const size_t base = (size_t)b * 2048 + (size_t)tid * 8;
    alignas(16) u16 o[8];
    const float4* s = (const float4*)((const float*)x + base);
    float4 v0 = s[0], v1 = s[1];
    o[0]=f2b(v0.x); o[1]=f2b(v0.y); o[2]=f2b(v0.z); o[3]=f2b(v0.w);
    o[4]=f2b(v1.x); o[5]=f2b(v1.y); o[6]=f2b(v1.z); o[7]=f2b(v1.w);
    *(uint4*)(xb + base) = *(const uint4*)o;
  } else if (b == 2048) {                    // ---- biases -> f32
    const int f3 = probe_f32(b1m, 1024, &sflag);
    const int f5 = probe_f32(b2m, 512, &sflag);
    const int f7 = probe_f32(b1l, 1024, &sflag);
    const int f9 = probe_f32(b2l, 512, &sflag);
    for (int i = tid; i < 5120; i += 256) {
      float v;
      if (i < 2048)      v = ld_in(b1m, f3, i);
      else if (i < 4096) v = ld_in(b1l, f7, i - 2048);
      else if (i < 4608) v = ld_in(b2m, f5, i - 4096);
      else               v = ld_in(b2l, f9, i - 4608);
      biasv[i] = v;
    }
  } else {                                   // ---- 64x64-tile transposes
    const int id = b - 2049, which = id >> 8, t = id & 255;
    const void* in; u16* out; int R, C;
    if (which == 0)      { in = w1m; out = W1t;                   R = XD; C = HD; }
    else if (which == 1) { in = w2m; out = W2tm;                  R = HD; C = YD; }
    else if (which == 2) { in = w1l; out = W1t + (size_t)HD * XD; R = XD; C = HD; }
    else                 { in = w2l; out = W2tl;                  R = HD; C = YD; }
    const int f = probe_f32(in, 1024, &sflag);
    transpose64(in, out, R, C, f, t, tile);
  }
}

// ---------------- merged GEMM1: h_{mu,lv} = relu(x @ [W1m|W1l] + b1) --------
// R6's measured-best structure EXACTLY (58 us): pure 2048-block grid,
// 128x128 tile, BK=64, XOR-swizzled LDS, XCD-aware N-fastest decode.
__global__ __launch_bounds__(256) void gemm1_kernel(
    const void* __restrict__ xraw, const u16* __restrict__ xb,
    const u16* __restrict__ W1t,    // [4096, 512]
    const float* __restrict__ bias, // [4096]
    u16* __restrict__ h_mu, u16* __restrict__ h_lv) {
  constexpr int K = XD;
  __shared__ alignas(16) u16 As[128 * 64];
  __shared__ alignas(16) u16 Bs[128 * 64];
  __shared__ int sflag;

  const u16* A = probe_f32(xraw, 1024, &sflag) ? xb : (const u16*)xraw;

  const int tid = threadIdx.x, wid = tid >> 6, lane = tid & 63;
  const int MT = NS / 128, NT = (2 * HD) / 128;   // 64, 32
  const int id = blockIdx.x;
  const int xcd = id & 7, slot = id >> 3;
  const int bm0 = (xcd * (MT >> 3) + slot / NT) * 128;
  const int bn0 = (slot % NT) * 128;

  const int mrow = (wid >> 1) * 64, ncol = (wid & 1) * 64;
  const int quad = lane >> 4, c16 = lane & 15, cswz = c16 & 7;
  const int srow = lane >> 3, sc = lane & 7;
  const int scg  = (sc ^ srow) * 8;

  f32x4 acc[4][4] = {};

  for (int k0 = 0; k0 < K; k0 += 64) {
#pragma unroll
    for (int j = 0; j < 4; ++j) {
      const int grp = wid * 4 + j, row = grp * 8 + srow;
      GLDS(A   + (size_t)(bm0 + row) * K + (k0 + scg), As + grp * 512);
      GLDS(W1t + (size_t)(bn0 + row) * K + (k0 + scg), Bs + grp * 512);
    }
    __syncthreads();
#pragma unroll
    for (int h = 0; h < 2; ++h) {
      const int off = ((h * 4 + quad) ^ cswz) * 8;
      bf16x8 af[4], bfr[4];
#pragma unroll
      for (int mi = 0; mi < 4; ++mi)
        af[mi] = *(const bf16x8*)&As[(mrow + mi * 16 + c16) * 64 + off];
#pragma unroll
      for (int ni = 0; ni < 4; ++ni)
        bfr[ni] = *(const bf16x8*)&Bs[(ncol + ni * 16 + c16) * 64 + off];
#pragma unroll
      for (int mi = 0; mi < 4; ++mi)
#pragma unroll
        for (int ni = 0; ni < 4; ++ni)
          acc[mi][ni] = __builtin_amdgcn_mfma_f32_16x16x32_bf16(
              af[mi], bfr[ni], acc[mi][ni], 0, 0, 0);
    }
    __syncthreads();
  }

  // Epilogue (C/D layout m89: col = lane&15, row = quad*4 + reg)
  const bool is_lv = bn0 >= HD;
  u16* dst = is_lv ? h_lv : h_mu;
  const int cb = bn0 - (is_lv ? HD : 0);
#pragma unroll
  for (int ni = 0; ni < 4; ++ni) {
    const int gc = ncol + ni * 16 + c16;
    const float bv = bias[bn0 + gc];
#pragma unroll
    for (int mi = 0; mi < 4; ++mi)
#pragma unroll
      for (int r = 0; r < 4; ++r) {
        const int grow = bm0 + mrow + mi * 16 + quad * 4 + r;
        dst[(size_t)grow * HD + (cb + gc)] = f2b(fmaxf(acc[mi][ni][r] + bv, 0.f));
      }
  }
}

// ---------------- gemm2: ystats head + dual-head GEMM + loss + finalize -----
// Blocks [0,64): y column stats (vectorized), then release ycnt.
// Blocks [64,576): R6-proven dual GEMM (32 MFMA/barrier); the epilogue
// spin-waits ycnt==64 (device-scope) — ystats (~10 us) finishes long before
// any ~45 us K-loop does, so the spin never actually waits. id-64 keeps the
// id&7 XCD decode dispatch-aligned (64 % 8 == 0). Last GEMM block finalizes.
__global__ __launch_bounds__(256) void gemm2_dual(
    const u16* __restrict__ hm, const u16* __restrict__ hl,
    const u16* __restrict__ W2m, const u16* __restrict__ W2l,  // [YD, HD]
    const float* __restrict__ b2m, const float* __restrict__ b2l,
    const void* __restrict__ y,
    float* __restrict__ Sy, float* __restrict__ Sy2,
    double* __restrict__ gacc, unsigned* __restrict__ counter,
    unsigned* __restrict__ ycnt, float* __restrict__ out) {
  constexpr int K = HD;
  __shared__ alignas(16) u16 Am[64 * 64];    // 8 KB
  __shared__ alignas(16) u16 Al[64 * 64];    // 8 KB
  __shared__ alignas(16) u16 Bm[128 * 64];   // 16 KB
  __shared__ alignas(16) u16 Bl[128 * 64];   // 16 KB
  __shared__ double bs[4];
  __shared__ int sflag;

  const int tid = threadIdx.x;
  const int yf = probe_f32(y, 1024, &sflag);

  if (blockIdx.x < 64) {                     // ---- ystats blocks
    const int half = tid >> 7;               // rows r0..+63 / r0+64..+127
    const int c0 = (tid & 127) * 4;          // cols c0..c0+3
    const int r0 = blockIdx.x * 128 + half * 64;
    float s0 = 0.f, s1 = 0.f, s2 = 0.f, s3 = 0.f;
    float q0 = 0.f, q1 = 0.f, q2 = 0.f, q3 = 0.f;
    for (int r = r0; r < r0 + 64; r += 4) {
#pragma unroll
      for (int rr = 0; rr < 4; ++rr) {
        float v0, v1, v2, v3;
        if (yf) {
          const float4 t4 = *(const float4*)((const float*)y + (size_t)(r + rr) * YD + c0);
          v0 = t4.x; v1 = t4.y; v2 = t4.z; v3 = t4.w;
        } else {
          const uint2 t2 = *(const uint2*)((const u16*)y + (size_t)(r + rr) * YD + c0);
          v0 = bf2f((u16)(t2.x & 0xffff)); v1 = bf2f((u16)(t2.x >> 16));
          v2 = bf2f((u16)(t2.y & 0xffff)); v3 = bf2f((u16)(t2.y >> 16));
        }
        s0 += v0; q0 += v0 * v0;  s1 += v1; q1 += v1 * v1;
        s2 += v2; q2 += v2 * v2;  s3 += v3; q3 += v3 * v3;
      }
    }
    atomicAdd(&Sy[c0],     s0);  atomicAdd(&Sy2[c0],     q0);
    atomicAdd(&Sy[c0 + 1], s1);  atomicAdd(&Sy2[c0 + 1], q1);
    atomicAdd(&Sy[c0 + 2], s2);  atomicAdd(&Sy2[c0 + 2], q2);
    atomicAdd(&Sy[c0 + 3], s3);  atomicAdd(&Sy2[c0 + 3], q3);
    __syncthreads();
    if (tid == 0) { __threadfence(); atomicAdd(ycnt, 1u); }
    return;
  }

  const int wid = tid >> 6, lane = tid & 63;
  const int MT = NS / 64, NT = YD / 128;     // 128, 4
  const int id = blockIdx.x - 64;
  const int xcd = id & 7, slot = id >> 3;
  const int bm0 = (xcd * (MT >> 3) + slot / NT) * 64;
  const int bn0 = (slot % NT) * 128;

  const int mrow = (wid >> 1) * 32, ncol = (wid & 1) * 64;
  const int quad = lane >> 4, c16 = lane & 15, cswz = c16 & 7;
  const int srow = lane >> 3, sc = lane & 7;
  const int scg  = (sc ^ srow) * 8;

  f32x4 am[2][4] = {}, al[2][4] = {};

  for (int k0 = 0; k0 < K; k0 += 64) {
#pragma unroll
    for (int j = 0; j < 2; ++j) {            // h tiles: 64 rows
      const int grp = wid * 2 + j, row = grp * 8 + srow;
      const size_t go = (size_t)(bm0 + row) * K + (k0 + scg);
      GLDS(hm + go, Am + grp * 512);
      GLDS(hl + go, Al + grp * 512);
    }
#pragma unroll
    for (int j = 0; j < 4; ++j) {            // W2 tiles: 128 rows
      const int grp = wid * 4 + j, row = grp * 8 + srow;
      const size_t go = (size_t)(bn0 + row) * K + (k0 + scg);
      GLDS(W2m + go, Bm + grp * 512);
      GLDS(W2l + go, Bl + grp * 512);
    }
    __syncthreads();
#pragma unroll
    for (int h = 0; h < 2; ++h) {
      const int off = ((h * 4 + quad) ^ cswz) * 8;
      bf16x8 afm[2], afl[2], bfm[4], bfl[4];
#pragma unroll
      for (int mi = 0; mi < 2; ++mi) {
        const int rl = (mrow + mi * 16 + c16) * 64 + off;
        afm[mi] = *(const bf16x8*)&Am[rl];
        afl[mi] = *(const bf16x8*)&Al[rl];
      }
#pragma unroll
      for (int ni = 0; ni < 4; ++ni) {
        const int rl = (ncol + ni * 16 + c16) * 64 + off;
        bfm[ni] = *(const bf16x8*)&Bm[rl];
        bfl[ni] = *(const bf16x8*)&Bl[rl];
      }
#pragma unroll
      for (int mi = 0; mi < 2; ++mi)
#pragma unroll
        for (int ni = 0; ni < 4; ++ni) {
          am[mi][ni] = __builtin_amdgcn_mfma_f32_16x16x32_bf16(
              afm[mi], bfm[ni], am[mi][ni], 0, 0, 0);
          al[mi][ni] = __builtin_amdgcn_mfma_f32_16x16x32_bf16(
              afl[mi], bfl[ni], al[mi][ni], 0, 0, 0);
        }
    }
    __syncthreads();
  }

  // Wait for ystats (device-scope; in practice already done ~35 us ago).
  if (tid == 0) {
    while (__hip_atomic_load(ycnt, __ATOMIC_ACQUIRE,
                             __HIP_MEMORY_SCOPE_AGENT) < 64u) {}
  }
  __syncthreads();

  // Fused loss epilogue: mu & lvp in registers.
  // term: w * [ y^2 - 2*mu*y + (2*mu*Sy_d - Sy2_d)/N ], w = 0.5*e^{-tanh(lvp)}
  const float invN = 1.0f / (float)NS;
  float s = 0.f;
#pragma unroll
  for (int ni = 0; ni < 4; ++ni) {
    const int gcol = bn0 + ncol + ni * 16 + c16;
    const float bmv = b2m[gcol], blv = b2l[gcol];
    const float syv = Sy[gcol], sy2v = Sy2[gcol];
#pragma unroll
    for (int mi = 0; mi < 2; ++mi)
#pragma unroll
      for (int r = 0; r < 4; ++r) {
        const int grow = bm0 + mrow + mi * 16 + quad * 4 + r;
        const float m   = am[mi][ni][r] + bmv;
        const float lvp = al[mi][ni][r] + blv;
        const float w   = 0.5f * expf(-tanhf(lvp));
        const float yv  = ld_in(y, yf, (size_t)grow * YD + gcol);
        s += w * (yv * yv - 2.f * m * yv + (2.f * m * syv - sy2v) * invN);
      }
  }
  for (int off = 32; off > 0; off >>= 1) s += __shfl_down(s, off);
  if (lane == 0) bs[wid] = (double)s;
  __syncthreads();
  if (tid == 0) {
    atomicAdd(gacc, bs[0] + bs[1] + bs[2] + bs[3]);
    __threadfence();
    const unsigned old = atomicAdd(counter, 1u);
    if (old == 511u) {                       // last of the 512 GEMM blocks
      const double g = atomicAdd(gacc, 0.0); // coherent read of final sum
      out[0] = (float)(-g / (double)NS);     // fp32 output (round-2 evidence)
    }
  }
}

// ---------------- launch ----------------
extern "C" void kernel_launch(void* const* d_in, const int* in_sizes, int n_in,
                              void* d_out, int out_size, void* d_ws, size_t ws_size,
                              hipStream_t stream) {
  char* ws = (char*)d_ws;
  double*   gacc    = (double*)ws;               // [0,8)
  unsigned* counter = (unsigned*)(ws + 8);       // [8,12)
  unsigned* ycnt    = (unsigned*)(ws + 12);      // [12,16)
  float*    Sy      = (float*)(ws + 128);        // 512 f32
  float*    Sy2     = (float*)(ws + 2176);       // 512 f32
  float*    biasv   = (float*)(ws + 4224);       // 5120 f32 -> ends 24704
  u16* xb   = (u16*)(ws + 24704);                // [NS,XD] bf16, 8 MB
  u16* W1t  = xb + (size_t)NS * XD;              // [4096,512] 4 MB (both heads)
  u16* W2tm = W1t + (size_t)2 * HD * XD;         // [YD,HD] 2 MB
  u16* W2tl = W2tm + (size_t)YD * HD;            // 2 MB
  u16* h_mu = W2tl + (size_t)YD * HD;            // [NS,HD] bf16, 32 MB
  u16* h_lv = h_mu + (size_t)NS * HD;            // 32 MB  (~80 MB total)

  hipMemsetAsync(d_ws, 0, 4224, stream);         // gacc+counter+ycnt+Sy+Sy2

  prep_all<<<2049 + 1024, 256, 0, stream>>>(
      d_in[0], d_in[2], d_in[3], d_in[4], d_in[5],
      d_in[6], d_in[7], d_in[8], d_in[9],
      xb, biasv, W1t, W2tm, W2tl);

  const float* b1  = biasv;               // [4096] = b1m|b1l
  const float* b2m = biasv + 4096, *b2l = biasv + 4608;

  gemm1_kernel<<<(NS / 128) * ((2 * HD) / 128), 256, 0, stream>>>(
      d_in[0], xb, W1t, b1, h_mu, h_lv);

  gemm2_dual<<<64 + (NS / 64) * (YD / 128), 256, 0, stream>>>(
      h_mu, h_lv, W2tm, W2tl, b2m, b2l, d_in[1], Sy, Sy2,
      gacc, counter, ycnt, (float*)d_out);
}

// Round 13
// 232.200 us; speedup vs baseline: 1.0597x; 1.0597x over previous
//
#include <hip/hip_runtime.h>
#include <hip/hip_bf16.h>
#include <stdint.h>

// Problem constants (fixed by the reference)
#define NS   8192
#define XD   512
#define HD   2048
#define YD   512

typedef unsigned short u16;
using bf16x8 = __attribute__((ext_vector_type(8))) short;
using f32x4  = __attribute__((ext_vector_type(4))) float;

__device__ __forceinline__ float bf2f(u16 u) {
  union { uint32_t i; float f; } v; v.i = ((uint32_t)u) << 16; return v.f;
}
__device__ __forceinline__ u16 f2b(float f) {
  __hip_bfloat16 hb = __float2bfloat16(f);
  return *(const u16*)&hb;
}
// dtype-adaptive element load: f32 flag ? read float : read bf16
__device__ __forceinline__ float ld_in(const void* p, int f32, size_t i) {
  return f32 ? ((const float*)p)[i] : bf2f(((const u16*)p)[i]);
}
#define GLDS(gp, lp) __builtin_amdgcn_global_load_lds( \
    (__attribute__((address_space(1))) void*)(gp),     \
    (__attribute__((address_space(3))) void*)(lp), 16, 0, 0)

// ---------------- per-block dtype self-detection ----------------------------
// (round-2/3 lesson: inputs are MIXED dtype; accounting says x,y = fp32,
// weights/biases = bf16 — but stay adaptive). fp32 bits read as bf16 are
// wild/NaN with p~0.46 per low-u16 -> 256+ sample probe is conclusive.
__device__ __forceinline__ int probe_f32(const void* p, int n_u16, int* sflag) {
  if (threadIdx.x == 0) *sflag = 0;
  __syncthreads();
  const u16* q = (const u16*)p;
  int wild = 0;
  for (int i = threadIdx.x; i < n_u16; i += blockDim.x) {
    float v = bf2f(q[i]);
    if (!(fabsf(v) <= 1000.0f)) wild = 1;   // catches huge AND NaN
  }
  if (wild) *sflag = 1;
  __syncthreads();
  int r = *sflag;
  __syncthreads();                          // safe for back-to-back reuse
  return r;
}

// ---------------- shared 64x64 transpose tile (bf16/f32 in -> bf16^T out) ---
__device__ __forceinline__ void transpose64(const void* in, u16* out,
                                            int R, int C, int f, int t,
                                            u16* tile /* >= 64*72 u16 */) {
  const int tid = threadIdx.x;
  const int nbx = C >> 6;
  const int c0 = (t % nbx) * 64, r0 = (t / nbx) * 64;
  const int r = tid >> 2, cc = (tid & 3) * 16;
  if (f) {
    const float4* s = (const float4*)((const float*)in + (size_t)(r0 + r) * C + c0 + cc);
#pragma unroll
    for (int k = 0; k < 4; ++k) {
      float4 v = s[k];
      tile[r * 72 + cc + k * 4 + 0] = f2b(v.x);
      tile[r * 72 + cc + k * 4 + 1] = f2b(v.y);
      tile[r * 72 + cc + k * 4 + 2] = f2b(v.z);
      tile[r * 72 + cc + k * 4 + 3] = f2b(v.w);
    }
  } else {
    const uint4* s = (const uint4*)((const u16*)in + (size_t)(r0 + r) * C + c0 + cc);
    *(uint4*)&tile[r * 72 + cc]     = s[0];
    *(uint4*)&tile[r * 72 + cc + 8] = s[1];
  }
  __syncthreads();
  const int i = tid >> 2, jc = (tid & 3) * 16;
  alignas(16) u16 o[16];
#pragma unroll
  for (int j = 0; j < 16; ++j) o[j] = tile[(jc + j) * 72 + i];
  uint4* dq = (uint4*)&out[(size_t)(c0 + i) * R + r0 + jc];
  dq[0] = ((const uint4*)o)[0];
  dq[1] = ((const uint4*)o)[1];
}

// ---------------- fused prep: ystats, x->bf16, biases(+zero), transposes ----
// R13 ledger conclusion (R9..R12): embedding latency blocks in MFMA grids
// costs the host 2-4x the work's standalone cost. Everything small lives HERE;
// both GEMMs get pure grids. No memset dispatch: bias block zeroes gacc/cnt.
// grid: [0,64) ystats | [64,2112) x-convert | 2112 biases+zero |
//       [2113,3137) 64x64 transposes (W1m, W2m, W1l, W2l)
// ystats is ATOMIC-FREE: block b owns cols [8b,8b+8) over all rows, reduces
// in LDS, stores Sy/Sy2 directly (no zero-init ordering hazard).
// biasv layout: [b1m(2048) | b1l(2048) | b2m(512) | b2l(512)]
// W1t combined: [4096, 512] = W1m^T rows 0..2047, W1l^T rows 2048..4095.
__global__ __launch_bounds__(256) void prep_all(
    const void* __restrict__ x, const void* __restrict__ y,
    const void* w1m, const void* b1m, const void* w2m, const void* b2m,
    const void* w1l, const void* b1l, const void* w2l, const void* b2l,
    u16* __restrict__ xb, float* __restrict__ biasv,
    float* __restrict__ Sy, float* __restrict__ Sy2,
    u16* __restrict__ W1t, u16* __restrict__ W2tm, u16* __restrict__ W2tl,
    double* __restrict__ gacc, unsigned* __restrict__ counter) {
  __shared__ alignas(16) u16 tile[64 * 72];  // 9216 B (transpose / ystats red)
  __shared__ int sflag;
  const int b = blockIdx.x;
  const int tid = threadIdx.x;

  if (b < 64) {                              // ---- ystats: cols [8b, 8b+8)
    const int yf = probe_f32(y, 1024, &sflag);
    const int c0 = b * 8;
    float s[8] = {}, q[8] = {};
    if (yf) {
      const float* fy = (const float*)y + c0;
      for (int r = tid; r < NS; r += 256) {
        const float4 a = *(const float4*)(fy + (size_t)r * YD);
        const float4 c = *(const float4*)(fy + (size_t)r * YD + 4);
        s[0]+=a.x; q[0]+=a.x*a.x; s[1]+=a.y; q[1]+=a.y*a.y;
        s[2]+=a.z; q[2]+=a.z*a.z; s[3]+=a.w; q[3]+=a.w*a.w;
        s[4]+=c.x; q[4]+=c.x*c.x; s[5]+=c.y; q[5]+=c.y*c.y;
        s[6]+=c.z; q[6]+=c.z*c.z; s[7]+=c.w; q[7]+=c.w*c.w;
      }
    } else {
      const u16* hy = (const u16*)y + c0;
      for (int r = tid; r < NS; r += 256) {
        const uint4 t4 = *(const uint4*)(hy + (size_t)r * YD);
        const uint32_t w4[4] = {t4.x, t4.y, t4.z, t4.w};
#pragma unroll
        for (int j = 0; j < 4; ++j) {
          const float v0 = bf2f((u16)(w4[j] & 0xffff));
          const float v1 = bf2f((u16)(w4[j] >> 16));
          s[2*j]   += v0; q[2*j]   += v0 * v0;
          s[2*j+1] += v1; q[2*j+1] += v1 * v1;
        }
      }
    }
    float* red = (float*)tile;               // 8 KB, two passes
#pragma unroll
    for (int j = 0; j < 8; ++j) red[j * 256 + tid] = s[j];
    __syncthreads();
    for (int st = 128; st > 0; st >>= 1) {
      if (tid < st)
#pragma unroll
        for (int j = 0; j < 8; ++j) red[j * 256 + tid] += red[j * 256 + tid + st];
      __syncthreads();
    }
    if (tid < 8) Sy[c0 + tid] = red[tid * 256];
    __syncthreads();
#pragma unroll
    for (int j = 0; j < 8; ++j) red[j * 256 + tid] = q[j];
    __syncthreads();
    for (int st = 128; st > 0; st >>= 1) {
      if (tid < st)
#pragma unroll
        for (int j = 0; j < 8; ++j) red[j * 256 + tid] += red[j * 256 + tid + st];
      __syncthreads();
    }
    if (tid < 8) Sy2[c0 + tid] = red[tid * 256];
  } else if (b < 2112) {                     // ---- x conversion (f32 only)
    if (!probe_f32(x, 1024, &sflag)) return; // bf16 -> gemm1 reads x directly
    const size_t base = (size_t)(b - 64) * 2048 + (size_t)tid * 8;
    alignas(16) u16 o[8];
    const float4* s = (const float4*)((const float*)x + base);
    float4 v0 = s[0], v1 = s[1];
    o[0]=f2b(v0.x); o[1]=f2b(v0.y); o[2]=f2b(v0.z); o[3]=f2b(v0.w);
    o[4]=f2b(v1.x); o[5]=f2b(v1.y); o[6]=f2b(v1.z); o[7]=f2b(v1.w);
    *(uint4*)(xb + base) = *(const uint4*)o;
  } else if (b == 2112) {                    // ---- biases -> f32, zero accs
    if (tid == 0) { *gacc = 0.0; *counter = 0u; }
    const int f3 = probe_f32(b1m, 1024, &sflag);
    const int f5 = probe_f32(b2m, 512, &sflag);
    const int f7 = probe_f32(b1l, 1024, &sflag);
    const int f9 = probe_f32(b2l, 512, &sflag);
    for (int i = tid; i < 5120; i += 256) {
      float v;
      if (i < 2048)      v = ld_in(b1m, f3, i);
      else if (i < 4096) v = ld_in(b1l, f7, i - 2048);
      else if (i < 4608) v = ld_in(b2m, f5, i - 4096);
      else               v = ld_in(b2l, f9, i - 4608);
      biasv[i] = v;
    }
  } else {                                   // ---- 64x64-tile transposes
    const int id = b - 2113, which = id >> 8, t = id & 255;
    const void* in; u16* out; int R, C;
    if (which == 0)      { in = w1m; out = W1t;                   R = XD; C = HD; }
    else if (which == 1) { in = w2m; out = W2tm;                  R = HD; C = YD; }
    else if (which == 2) { in = w1l; out = W1t + (size_t)HD * XD; R = XD; C = HD; }
    else                 { in = w2l; out = W2tl;                  R = HD; C = YD; }
    const int f = probe_f32(in, 1024, &sflag);
    transpose64(in, out, R, C, f, t, tile);
  }
}

// ---------------- merged GEMM1: h_{mu,lv} = relu(x @ [W1m|W1l] + b1) --------
// R6's measured-best structure EXACTLY (58 us): pure 2048-block grid,
// 128x128 tile, BK=64, XOR-swizzled LDS, XCD-aware N-fastest decode.
__global__ __launch_bounds__(256) void gemm1_kernel(
    const void* __restrict__ xraw, const u16* __restrict__ xb,
    const u16* __restrict__ W1t,    // [4096, 512]
    const float* __restrict__ bias, // [4096]
    u16* __restrict__ h_mu, u16* __restrict__ h_lv) {
  constexpr int K = XD;
  __shared__ alignas(16) u16 As[128 * 64];
  __shared__ alignas(16) u16 Bs[128 * 64];
  __shared__ int sflag;

  const u16* A = probe_f32(xraw, 1024, &sflag) ? xb : (const u16*)xraw;

  const int tid = threadIdx.x, wid = tid >> 6, lane = tid & 63;
  const int MT = NS / 128, NT = (2 * HD) / 128;   // 64, 32
  const int id = blockIdx.x;
  const int xcd = id & 7, slot = id >> 3;
  const int bm0 = (xcd * (MT >> 3) + slot / NT) * 128;
  const int bn0 = (slot % NT) * 128;

  const int mrow = (wid >> 1) * 64, ncol = (wid & 1) * 64;
  const int quad = lane >> 4, c16 = lane & 15, cswz = c16 & 7;
  const int srow = lane >> 3, sc = lane & 7;
  const int scg  = (sc ^ srow) * 8;

  f32x4 acc[4][4] = {};

  for (int k0 = 0; k0 < K; k0 += 64) {
#pragma unroll
    for (int j = 0; j < 4; ++j) {
      const int grp = wid * 4 + j, row = grp * 8 + srow;
      GLDS(A   + (size_t)(bm0 + row) * K + (k0 + scg), As + grp * 512);
      GLDS(W1t + (size_t)(bn0 + row) * K + (k0 + scg), Bs + grp * 512);
    }
    __syncthreads();
#pragma unroll
    for (int h = 0; h < 2; ++h) {
      const int off = ((h * 4 + quad) ^ cswz) * 8;
      bf16x8 af[4], bfr[4];
#pragma unroll
      for (int mi = 0; mi < 4; ++mi)
        af[mi] = *(const bf16x8*)&As[(mrow + mi * 16 + c16) * 64 + off];
#pragma unroll
      for (int ni = 0; ni < 4; ++ni)
        bfr[ni] = *(const bf16x8*)&Bs[(ncol + ni * 16 + c16) * 64 + off];
#pragma unroll
      for (int mi = 0; mi < 4; ++mi)
#pragma unroll
        for (int ni = 0; ni < 4; ++ni)
          acc[mi][ni] = __builtin_amdgcn_mfma_f32_16x16x32_bf16(
              af[mi], bfr[ni], acc[mi][ni], 0, 0, 0);
    }
    __syncthreads();
  }

  // Epilogue (C/D layout m89: col = lane&15, row = quad*4 + reg)
  const bool is_lv = bn0 >= HD;
  u16* dst = is_lv ? h_lv : h_mu;
  const int cb = bn0 - (is_lv ? HD : 0);
#pragma unroll
  for (int ni = 0; ni < 4; ++ni) {
    const int gc = ncol + ni * 16 + c16;
    const float bv = bias[bn0 + gc];
#pragma unroll
    for (int mi = 0; mi < 4; ++mi)
#pragma unroll
      for (int r = 0; r < 4; ++r) {
        const int grow = bm0 + mrow + mi * 16 + quad * 4 + r;
        dst[(size_t)grow * HD + (cb + gc)] = f2b(fmaxf(acc[mi][ni][r] + bv, 0.f));
      }
  }
}

// ---------------- dual-head GEMM2 + fused loss + last-block finalize --------
// R6-proven structure, CLEAN 512-block grid (R12 measured embedding ystats
// here at +45 us). Every wave computes BOTH heads on a 32x128 strip (dual
// accumulators, 32 MFMA per barrier); epilogue computes mu & lvp in registers
// -> loss directly. Last finishing block writes the fp32 output scalar
// (gacc/counter pre-zeroed by prep; kernel-boundary ordering guarantees it).
__global__ __launch_bounds__(256) void gemm2_dual(
    const u16* __restrict__ hm, const u16* __restrict__ hl,
    const u16* __restrict__ W2m, const u16* __restrict__ W2l,  // [YD, HD]
    const float* __restrict__ b2m, const float* __restrict__ b2l,
    const void* __restrict__ y,
    const float* __restrict__ Sy, const float* __restrict__ Sy2,
    double* __restrict__ gacc, unsigned* __restrict__ counter,
    float* __restrict__ out) {
  constexpr int K = HD;
  __shared__ alignas(16) u16 Am[64 * 64];    // 8 KB
  __shared__ alignas(16) u16 Al[64 * 64];    // 8 KB
  __shared__ alignas(16) u16 Bm[128 * 64];   // 16 KB
  __shared__ alignas(16) u16 Bl[128 * 64];   // 16 KB
  __shared__ double bs[4];
  __shared__ int sflag;

  const int yf = probe_f32(y, 1024, &sflag);

  const int tid = threadIdx.x, wid = tid >> 6, lane = tid & 63;
  const int MT = NS / 64, NT = YD / 128;     // 128, 4
  const int id = blockIdx.x;
  const int xcd = id & 7, slot = id >> 3;
  const int bm0 = (xcd * (MT >> 3) + slot / NT) * 64;
  const int bn0 = (slot % NT) * 128;

  const int mrow = (wid >> 1) * 32, ncol = (wid & 1) * 64;
  const int quad = lane >> 4, c16 = lane & 15, cswz = c16 & 7;
  const int srow = lane >> 3, sc = lane & 7;
  const int scg  = (sc ^ srow) * 8;

  f32x4 am[2][4] = {}, al[2][4] = {};

  for (int k0 = 0; k0 < K; k0 += 64) {
#pragma unroll
    for (int j = 0; j < 2; ++j) {            // h tiles: 64 rows
      const int grp = wid * 2 + j, row = grp * 8 + srow;
      const size_t go = (size_t)(bm0 + row) * K + (k0 + scg);
      GLDS(hm + go, Am + grp * 512);
      GLDS(hl + go, Al + grp * 512);
    }
#pragma unroll
    for (int j = 0; j < 4; ++j) {            // W2 tiles: 128 rows
      const int grp = wid * 4 + j, row = grp * 8 + srow;
      const size_t go = (size_t)(bn0 + row) * K + (k0 + scg);
      GLDS(W2m + go, Bm + grp * 512);
      GLDS(W2l + go, Bl + grp * 512);
    }
    __syncthreads();
#pragma unroll
    for (int h = 0; h < 2; ++h) {
      const int off = ((h * 4 + quad) ^ cswz) * 8;
      bf16x8 afm[2], afl[2], bfm[4], bfl[4];
#pragma unroll
      for (int mi = 0; mi < 2; ++mi) {
        const int rl = (mrow + mi * 16 + c16) * 64 + off;
        afm[mi] = *(const bf16x8*)&Am[rl];
        afl[mi] = *(const bf16x8*)&Al[rl];
      }
#pragma unroll
      for (int ni = 0; ni < 4; ++ni) {
        const int rl = (ncol + ni * 16 + c16) * 64 + off;
        bfm[ni] = *(const bf16x8*)&Bm[rl];
        bfl[ni] = *(const bf16x8*)&Bl[rl];
      }
#pragma unroll
      for (int mi = 0; mi < 2; ++mi)
#pragma unroll
        for (int ni = 0; ni < 4; ++ni) {
          am[mi][ni] = __builtin_amdgcn_mfma_f32_16x16x32_bf16(
              afm[mi], bfm[ni], am[mi][ni], 0, 0, 0);
          al[mi][ni] = __builtin_amdgcn_mfma_f32_16x16x32_bf16(
              afl[mi], bfl[ni], al[mi][ni], 0, 0, 0);
        }
    }
    __syncthreads();
  }

  // Fused loss epilogue: mu & lvp in registers.
  // term: w * [ y^2 - 2*mu*y + (2*mu*Sy_d - Sy2_d)/N ], w = 0.5*e^{-tanh(lvp)}
  const float invN = 1.0f / (float)NS;
  float s = 0.f;
#pragma unroll
  for (int ni = 0; ni < 4; ++ni) {
    const int gcol = bn0 + ncol + ni * 16 + c16;
    const float bmv = b2m[gcol], blv = b2l[gcol];
    const float syv = Sy[gcol], sy2v = Sy2[gcol];
#pragma unroll
    for (int mi = 0; mi < 2; ++mi)
#pragma unroll
      for (int r = 0; r < 4; ++r) {
        const int grow = bm0 + mrow + mi * 16 + quad * 4 + r;
        const float m   = am[mi][ni][r] + bmv;
        const float lvp = al[mi][ni][r] + blv;
        const float w   = 0.5f * expf(-tanhf(lvp));
        const float yv  = ld_in(y, yf, (size_t)grow * YD + gcol);
        s += w * (yv * yv - 2.f * m * yv + (2.f * m * syv - sy2v) * invN);
      }
  }
  for (int off = 32; off > 0; off >>= 1) s += __shfl_down(s, off);
  if (lane == 0) bs[wid] = (double)s;
  __syncthreads();
  if (tid == 0) {
    atomicAdd(gacc, bs[0] + bs[1] + bs[2] + bs[3]);
    __threadfence();
    const unsigned old = atomicAdd(counter, 1u);
    if (old == 511u) {                       // last of 512 blocks
      const double g = atomicAdd(gacc, 0.0); // coherent read of final sum
      out[0] = (float)(-g / (double)NS);     // fp32 output (round-2 evidence)
    }
  }
}

// ---------------- launch: 3 dispatches, no memset ---------------------------
extern "C" void kernel_launch(void* const* d_in, const int* in_sizes, int n_in,
                              void* d_out, int out_size, void* d_ws, size_t ws_size,
                              hipStream_t stream) {
  char* ws = (char*)d_ws;
  double*   gacc    = (double*)ws;               // [0,8)   zeroed by prep
  unsigned* counter = (unsigned*)(ws + 8);       // [8,12)  zeroed by prep
  float*    Sy      = (float*)(ws + 128);        // 512 f32 written by prep
  float*    Sy2     = (float*)(ws + 2176);       // 512 f32 written by prep
  float*    biasv   = (float*)(ws + 4224);       // 5120 f32 -> ends 24704
  u16* xb   = (u16*)(ws + 24704);                // [NS,XD] bf16, 8 MB
  u16* W1t  = xb + (size_t)NS * XD;              // [4096,512] 4 MB (both heads)
  u16* W2tm = W1t + (size_t)2 * HD * XD;         // [YD,HD] 2 MB
  u16* W2tl = W2tm + (size_t)YD * HD;            // 2 MB
  u16* h_mu = W2tl + (size_t)YD * HD;            // [NS,HD] bf16, 32 MB
  u16* h_lv = h_mu + (size_t)NS * HD;            // 32 MB  (~80 MB total)

  prep_all<<<3137, 256, 0, stream>>>(
      d_in[0], d_in[1], d_in[2], d_in[3], d_in[4], d_in[5],
      d_in[6], d_in[7], d_in[8], d_in[9],
      xb, biasv, Sy, Sy2, W1t, W2tm, W2tl, gacc, counter);

  const float* b1  = biasv;               // [4096] = b1m|b1l
  const float* b2m = biasv + 4096, *b2l = biasv + 4608;

  gemm1_kernel<<<(NS / 128) * ((2 * HD) / 128), 256, 0, stream>>>(
      d_in[0], xb, W1t, b1, h_mu, h_lv);

  gemm2_dual<<<(NS / 64) * (YD / 128), 256, 0, stream>>>(
      h_mu, h_lv, W2tm, W2tl, b2m, b2l, d_in[1], Sy, Sy2,
      gacc, counter, (float*)d_out);
}